// Round 2
// baseline (71.826 us; speedup 1.0000x reference)
//
#include <hip/hip_runtime.h>
#include <math.h>

// Problem: out[b,j] = act_{ids[496+j]}( x[b,:64] @ W[:64, 496+j] + bias[496+j] )
// B=65536, N=512, N_IN=64, N_OUT=16. Pure memory-streaming: ~21 MB total.

typedef __bf16 bf16x8 __attribute__((ext_vector_type(8)));
typedef float floatx4 __attribute__((ext_vector_type(4)));

#define NN_N 512
#define NN_NIN 64
#define NN_NOUT 16
#define TPW 4   // tiles (of 16 rows) per wave iteration

__global__ __launch_bounds__(256) void NeuralNetwork_74466142978489_kernel(
    const float* __restrict__ x,     // [B, 64]
    const float* __restrict__ W,     // [512, 512] row-major
    const float* __restrict__ bias,  // [512]
    const int*   __restrict__ acts,  // [512]
    float* __restrict__ out,         // [B, 16]
    int num_groups)                  // B / (16*TPW)
{
    const int lane = threadIdx.x & 63;
    const int wave = (int)((blockIdx.x * blockDim.x + threadIdx.x) >> 6);
    const int nwaves = (int)((gridDim.x * blockDim.x) >> 6);
    const int m    = lane & 15;   // A-row within tile == output column n
    const int quad = lane >> 4;
    const int gcol = NN_N - NN_NOUT + m;   // 496 + n

    // ---- Prologue (once per wave, amortized over TPW * iterations tiles) ----
    // B fragment: W[k, 496+n], k = t*32 + quad*8 + j. 64x16 slice, L2-hot.
    bf16x8 bfrag0, bfrag1;
#pragma unroll
    for (int j = 0; j < 8; ++j) {
        int k0 = quad * 8 + j;
        bfrag0[j] = (__bf16)W[(size_t)k0 * NN_N + gcol];
        bfrag1[j] = (__bf16)W[(size_t)(k0 + 32) * NN_N + gcol];
    }
    const float bval = bias[gcol];
    const int aid = acts[gcol];

    // Branchless activation constants (per-lane uniform across the loop):
    //   aid 0 (tanh):    y = 2*sigmoid(2v) - 1
    //   aid 1 (sigmoid): y = 1*sigmoid(1v) + 0
    //   aid 2 (relu):    y = fmax(v, 0.00*v)
    //   aid 3 (leaky):   y = fmax(v, 0.01*v)
    //   aid 4 (ident):   y = fmax(v, 1.00*v)
    const bool  is_sig = (aid < 2);
    const float sA = (aid == 0) ? 2.0f : 1.0f;   // output scale
    const float sB = (aid == 0) ? 2.0f : 1.0f;   // input scale
    const float sC = (aid == 0) ? -1.0f : 0.0f;  // output offset
    const float lc = (aid == 3) ? 0.01f : ((aid == 4) ? 1.0f : 0.0f);

    for (int g = wave; g < num_groups; g += nwaves) {
        const int tile0 = g * TPW;

        // Issue ALL loads for the group first (16 x dwordx4 in flight).
        floatx4 a[TPW][4];
#pragma unroll
        for (int t = 0; t < TPW; ++t) {
            const float* row = x + (size_t)((tile0 + t) * 16 + m) * NN_NIN
                                 + quad * 8;
            a[t][0] = __builtin_nontemporal_load((const floatx4*)(row));
            a[t][1] = __builtin_nontemporal_load((const floatx4*)(row + 4));
            a[t][2] = __builtin_nontemporal_load((const floatx4*)(row + 32));
            a[t][3] = __builtin_nontemporal_load((const floatx4*)(row + 36));
        }

#pragma unroll
        for (int t = 0; t < TPW; ++t) {
            bf16x8 af0, af1;
#pragma unroll
            for (int j = 0; j < 4; ++j) {
                af0[j]     = (__bf16)a[t][0][j];
                af0[4 + j] = (__bf16)a[t][1][j];
                af1[j]     = (__bf16)a[t][2][j];
                af1[4 + j] = (__bf16)a[t][3][j];
            }
            floatx4 acc = {bval, bval, bval, bval};
            acc = __builtin_amdgcn_mfma_f32_16x16x32_bf16(af0, bfrag0, acc, 0, 0, 0);
            acc = __builtin_amdgcn_mfma_f32_16x16x32_bf16(af1, bfrag1, acc, 0, 0, 0);

            // D layout: col = lane&15 (=m), row = quad*4 + r.
            float* obase = out + (size_t)((tile0 + t) * 16 + quad * 4) * NN_NOUT + m;
#pragma unroll
            for (int r = 0; r < 4; ++r) {
                const float v = acc[r];
                const float lin = fmaxf(v, lc * v);
                const float s = 1.0f / (1.0f + __expf(-sB * v));
                const float sig = fmaf(sA, s, sC);
                const float y = is_sig ? sig : lin;
                __builtin_nontemporal_store(y, obase + r * NN_NOUT);
            }
        }
    }
}

extern "C" void kernel_launch(void* const* d_in, const int* in_sizes, int n_in,
                              void* d_out, int out_size, void* d_ws, size_t ws_size,
                              hipStream_t stream) {
    const float* x    = (const float*)d_in[0];
    const float* W    = (const float*)d_in[1];
    const float* bias = (const float*)d_in[2];
    const int*   acts = (const int*)d_in[3];
    float* out = (float*)d_out;

    const int B = in_sizes[0] / NN_NIN;           // 65536
    const int num_tiles = B / 16;                 // 4096
    const int num_groups = num_tiles / TPW;       // 1024

    // 1024 waves = 256 blocks x 256 threads; each wave: 1 group of 4 tiles.
    const int block = 256;
    const int grid = 256;

    NeuralNetwork_74466142978489_kernel<<<grid, block, 0, stream>>>(
        x, W, bias, acts, out, num_groups);
}

// Round 3
// 71.006 us; speedup vs baseline: 1.0116x; 1.0116x over previous
//
#include <hip/hip_runtime.h>
#include <math.h>

// Problem: out[b,j] = act_{ids[496+j]}( x[b,:64] @ W[:64, 496+j] + bias[496+j] )
// B=65536, N=512, N_IN=64, N_OUT=16. Pure memory-streaming: ~21 MB total.
// R3: TPW=2, 2048 waves (8 waves/CU) — amortized prologue AND enough TLP.

typedef __bf16 bf16x8 __attribute__((ext_vector_type(8)));
typedef float floatx4 __attribute__((ext_vector_type(4)));

#define NN_N 512
#define NN_NIN 64
#define NN_NOUT 16
#define TPW 2   // tiles (of 16 rows) per wave iteration

__global__ __launch_bounds__(256) void NeuralNetwork_74466142978489_kernel(
    const float* __restrict__ x,     // [B, 64]
    const float* __restrict__ W,     // [512, 512] row-major
    const float* __restrict__ bias,  // [512]
    const int*   __restrict__ acts,  // [512]
    float* __restrict__ out,         // [B, 16]
    int num_groups)                  // B / (16*TPW)
{
    const int lane = threadIdx.x & 63;
    const int wave = (int)((blockIdx.x * blockDim.x + threadIdx.x) >> 6);
    const int nwaves = (int)((gridDim.x * blockDim.x) >> 6);
    const int m    = lane & 15;   // A-row within tile == output column n
    const int quad = lane >> 4;
    const int gcol = NN_N - NN_NOUT + m;   // 496 + n

    // ---- Prologue (once per wave) ----
    // B fragment: W[k, 496+n], k = t*32 + quad*8 + j. 64x16 slice, L2-hot.
    bf16x8 bfrag0, bfrag1;
#pragma unroll
    for (int j = 0; j < 8; ++j) {
        int k0 = quad * 8 + j;
        bfrag0[j] = (__bf16)W[(size_t)k0 * NN_N + gcol];
        bfrag1[j] = (__bf16)W[(size_t)(k0 + 32) * NN_N + gcol];
    }
    const float bval = bias[gcol];
    const int aid = acts[gcol];

    // Branchless activation constants (per-lane uniform across the loop).
    const bool  is_sig = (aid < 2);
    const float sA = (aid == 0) ? 2.0f : 1.0f;   // output scale
    const float sB = (aid == 0) ? 2.0f : 1.0f;   // input scale
    const float sC = (aid == 0) ? -1.0f : 0.0f;  // output offset
    const float lc = (aid == 3) ? 0.01f : ((aid == 4) ? 1.0f : 0.0f);

    for (int g = wave; g < num_groups; g += nwaves) {
        const int tile0 = g * TPW;

        // Issue ALL loads for the group first (TPW*4 dwordx4 in flight).
        floatx4 a[TPW][4];
#pragma unroll
        for (int t = 0; t < TPW; ++t) {
            const float* row = x + (size_t)((tile0 + t) * 16 + m) * NN_NIN
                                 + quad * 8;
            a[t][0] = __builtin_nontemporal_load((const floatx4*)(row));
            a[t][1] = __builtin_nontemporal_load((const floatx4*)(row + 4));
            a[t][2] = __builtin_nontemporal_load((const floatx4*)(row + 32));
            a[t][3] = __builtin_nontemporal_load((const floatx4*)(row + 36));
        }

#pragma unroll
        for (int t = 0; t < TPW; ++t) {
            bf16x8 af0, af1;
#pragma unroll
            for (int j = 0; j < 4; ++j) {
                af0[j]     = (__bf16)a[t][0][j];
                af0[4 + j] = (__bf16)a[t][1][j];
                af1[j]     = (__bf16)a[t][2][j];
                af1[4 + j] = (__bf16)a[t][3][j];
            }
            floatx4 acc = {bval, bval, bval, bval};
            acc = __builtin_amdgcn_mfma_f32_16x16x32_bf16(af0, bfrag0, acc, 0, 0, 0);
            acc = __builtin_amdgcn_mfma_f32_16x16x32_bf16(af1, bfrag1, acc, 0, 0, 0);

            // D layout: col = lane&15 (=m), row = quad*4 + r.
            float* obase = out + (size_t)((tile0 + t) * 16 + quad * 4) * NN_NOUT + m;
#pragma unroll
            for (int r = 0; r < 4; ++r) {
                const float v = acc[r];
                const float lin = fmaxf(v, lc * v);
                const float s = 1.0f / (1.0f + __expf(-sB * v));
                const float sig = fmaf(sA, s, sC);
                const float y = is_sig ? sig : lin;
                __builtin_nontemporal_store(y, obase + r * NN_NOUT);
            }
        }
    }
}

extern "C" void kernel_launch(void* const* d_in, const int* in_sizes, int n_in,
                              void* d_out, int out_size, void* d_ws, size_t ws_size,
                              hipStream_t stream) {
    const float* x    = (const float*)d_in[0];
    const float* W    = (const float*)d_in[1];
    const float* bias = (const float*)d_in[2];
    const int*   acts = (const int*)d_in[3];
    float* out = (float*)d_out;

    const int B = in_sizes[0] / NN_NIN;           // 65536
    const int num_tiles = B / 16;                 // 4096
    const int num_groups = num_tiles / TPW;       // 2048

    // 2048 waves = 512 blocks x 256 threads (8 waves/CU); 1 group/wave.
    const int block = 256;
    const int grid = 512;

    NeuralNetwork_74466142978489_kernel<<<grid, block, 0, stream>>>(
        x, W, bias, acts, out, num_groups);
}